// Round 1
// baseline (214.164 us; speedup 1.0000x reference)
//
#include <hip/hip_runtime.h>

// Chamfer loss: B=32, N=M=2048, D=3, fp32 in, scalar fp32 out.
// loss = sum_b [ sum_m min_n d2(x_bn, y_bm) + sum_n min_m d2(x_bn, y_bm) ] / B
//
// Strategy: 2 directions x 32 batches x 8 chunks = 512 blocks of 256 threads.
// Each block stages the full opposing point cloud in LDS (2048 x float4 = 32KB,
// w unused), each thread holds one query point in registers and scans all 2048
// staged points with uniform-address (broadcast) LDS reads. VALU-bound.

constexpr int B_SZ   = 32;
constexpr int NPTS   = 2048;
constexpr int BLOCK  = 256;
constexpr int CHUNKS = NPTS / BLOCK;  // 8

__global__ __launch_bounds__(BLOCK, 2)
void chamfer_kernel(const float* __restrict__ x, const float* __restrict__ y,
                    float* __restrict__ out) {
    __shared__ float4 pts[NPTS];          // 32 KB
    __shared__ float  wsum[BLOCK / 64];

    const int id    = blockIdx.x;
    const int dir   = id >> 8;                 // / (B_SZ*CHUNKS) = /256
    const int rem   = id & 255;
    const int b     = rem >> 3;                // / CHUNKS
    const int chunk = rem & (CHUNKS - 1);

    // dir 0: queries = x, staged = y  (out_dist_in: min over m for each n)
    // dir 1: queries = y, staged = x  (in_dist_out: min over n for each m)
    const float* qbase = (dir == 0) ? x : y;
    const float* pbase = (dir == 0) ? y : x;
    const float* q = qbase + (size_t)b * NPTS * 3;
    const float* p = pbase + (size_t)b * NPTS * 3;

    // Stage opposing cloud: coalesced global reads, scatter to padded float4.
    for (int idx = threadIdx.x; idx < NPTS * 3; idx += BLOCK) {
        int pt = idx / 3;          // magic-mul
        int c  = idx - pt * 3;
        ((float*)&pts[pt])[c] = p[idx];
    }
    __syncthreads();

    const int qi = chunk * BLOCK + threadIdx.x;
    const float qx = q[qi * 3 + 0];
    const float qy = q[qi * 3 + 1];
    const float qz = q[qi * 3 + 2];

    float best = 1e30f;
    #pragma unroll 8
    for (int n = 0; n < NPTS; ++n) {
        float4 pp = pts[n];        // uniform address -> LDS broadcast read
        float dx = qx - pp.x;
        float dy = qy - pp.y;
        float dz = qz - pp.z;
        float d = fmaf(dx, dx, fmaf(dy, dy, dz * dz));
        best = fminf(best, d);
    }

    // Sum of per-query mins: wave reduce, then cross-wave via LDS.
    float s = best;
    #pragma unroll
    for (int off = 32; off > 0; off >>= 1) s += __shfl_down(s, off, 64);
    const int lane = threadIdx.x & 63;
    const int wv   = threadIdx.x >> 6;
    if (lane == 0) wsum[wv] = s;
    __syncthreads();
    if (threadIdx.x == 0) {
        float t = 0.f;
        #pragma unroll
        for (int w = 0; w < BLOCK / 64; ++w) t += wsum[w];
        atomicAdd(out, t * (1.0f / B_SZ));
    }
}

extern "C" void kernel_launch(void* const* d_in, const int* in_sizes, int n_in,
                              void* d_out, int out_size, void* d_ws, size_t ws_size,
                              hipStream_t stream) {
    const float* x = (const float*)d_in[0];
    const float* y = (const float*)d_in[1];
    float* out = (float*)d_out;

    // d_out is poisoned (0xAA) before every timed replay — zero it first.
    hipMemsetAsync(out, 0, sizeof(float) * out_size, stream);

    chamfer_kernel<<<2 * B_SZ * CHUNKS, BLOCK, 0, stream>>>(x, y, out);
}

// Round 2
// 99.568 us; speedup vs baseline: 2.1509x; 2.1509x over previous
//
#include <hip/hip_runtime.h>

// Chamfer loss: B=32, N=M=2048, D=3, fp32 in, scalar fp32 out.
// loss = sum_b [ sum_m min_n d2 + sum_n min_m d2 ] / B
//
// v2: latency-bound fix. Q=2 queries/thread (1 broadcast ds_read_b128 feeds
// 14 VALU ops, two independent min chains), staged cloud split across 2
// blocks (SSPLIT=2) so grid stays at 512 blocks (8 waves/CU, 2/SIMD).
// Partial per-query mins combined with atomicMin on uint bit patterns
// (valid for non-negative floats), then a small reduce kernel sums them.

constexpr int B_SZ    = 32;
constexpr int NPTS    = 2048;
constexpr int BLOCK   = 256;
constexpr int QPT     = 2;                 // queries per thread
constexpr int QBLK    = BLOCK * QPT;       // 512 queries per block
constexpr int QCHUNKS = NPTS / QBLK;       // 4

template <int SSPLIT, bool TOWS>
__global__ __launch_bounds__(BLOCK, 2)
void chamfer_min_kernel(const float* __restrict__ x, const float* __restrict__ y,
                        unsigned int* __restrict__ ws, float* __restrict__ out) {
    constexpr int SPTS = NPTS / SSPLIT;    // staged points per block
    __shared__ float4 pts[SPTS];           // 16 KB (SSPLIT=2) / 32 KB (=1)
    __shared__ float  wsum[BLOCK / 64];

    const int id  = blockIdx.x;
    const int sh  = id % SSPLIT;
    const int t1  = id / SSPLIT;
    const int qc  = t1 % QCHUNKS;
    const int t2  = t1 / QCHUNKS;
    const int b   = t2 % B_SZ;
    const int dir = t2 / B_SZ;

    const float* qb = (dir == 0) ? x : y;
    const float* pb = (dir == 0) ? y : x;
    const float* q  = qb + (size_t)b * NPTS * 3;
    const float* p  = pb + (size_t)b * NPTS * 3 + sh * SPTS * 3;

    // Stage this block's slice of the opposing cloud (coalesced reads).
    for (int idx = threadIdx.x; idx < SPTS * 3; idx += BLOCK) {
        int pt = idx / 3;
        int c  = idx - pt * 3;
        ((float*)&pts[pt])[c] = p[idx];
    }
    __syncthreads();

    // Two queries per thread, BLOCK-strided so global loads stay coalesced.
    const int qi0 = qc * QBLK + threadIdx.x;
    const int qi1 = qi0 + BLOCK;
    const float q0x = q[qi0 * 3 + 0], q0y = q[qi0 * 3 + 1], q0z = q[qi0 * 3 + 2];
    const float q1x = q[qi1 * 3 + 0], q1y = q[qi1 * 3 + 1], q1z = q[qi1 * 3 + 2];

    float best0 = 3.0e38f, best1 = 3.0e38f;
    #pragma unroll 8
    for (int n = 0; n < SPTS; ++n) {
        float4 pp = pts[n];                // uniform addr -> LDS broadcast
        float dx0 = q0x - pp.x, dy0 = q0y - pp.y, dz0 = q0z - pp.z;
        float d0  = fmaf(dx0, dx0, fmaf(dy0, dy0, dz0 * dz0));
        float dx1 = q1x - pp.x, dy1 = q1y - pp.y, dz1 = q1z - pp.z;
        float d1  = fmaf(dx1, dx1, fmaf(dy1, dy1, dz1 * dz1));
        best0 = fminf(best0, d0);
        best1 = fminf(best1, d1);
    }

    if (TOWS) {
        // Combine partial mins across staged halves: uint atomicMin is
        // order-preserving for non-negative IEEE floats.
        unsigned int base = (unsigned int)(dir * B_SZ + b) * NPTS;
        atomicMin(&ws[base + qi0], __float_as_uint(best0));
        atomicMin(&ws[base + qi1], __float_as_uint(best1));
    } else {
        // SSPLIT==1 fallback: mins are complete, sum directly.
        float s = best0 + best1;
        #pragma unroll
        for (int off = 32; off > 0; off >>= 1) s += __shfl_down(s, off, 64);
        const int lane = threadIdx.x & 63;
        const int wv   = threadIdx.x >> 6;
        if (lane == 0) wsum[wv] = s;
        __syncthreads();
        if (threadIdx.x == 0) {
            float t = 0.f;
            #pragma unroll
            for (int w = 0; w < BLOCK / 64; ++w) t += wsum[w];
            atomicAdd(out, t * (1.0f / B_SZ));
        }
    }
}

// Sum 2*B_SZ*NPTS = 131072 mins -> scalar.  128 blocks x 256 thr, 1 float4 ea.
__global__ __launch_bounds__(256)
void chamfer_reduce_kernel(const float* __restrict__ ws, float* __restrict__ out) {
    __shared__ float wsum[4];
    const int i = blockIdx.x * 256 + threadIdx.x;
    float4 v = ((const float4*)ws)[i];
    float s = (v.x + v.y) + (v.z + v.w);
    #pragma unroll
    for (int off = 32; off > 0; off >>= 1) s += __shfl_down(s, off, 64);
    const int lane = threadIdx.x & 63;
    const int wv   = threadIdx.x >> 6;
    if (lane == 0) wsum[wv] = s;
    __syncthreads();
    if (threadIdx.x == 0) {
        float t = (wsum[0] + wsum[1]) + (wsum[2] + wsum[3]);
        atomicAdd(out, t * (1.0f / B_SZ));
    }
}

extern "C" void kernel_launch(void* const* d_in, const int* in_sizes, int n_in,
                              void* d_out, int out_size, void* d_ws, size_t ws_size,
                              hipStream_t stream) {
    const float* x = (const float*)d_in[0];
    const float* y = (const float*)d_in[1];
    float* out = (float*)d_out;

    hipMemsetAsync(out, 0, sizeof(float) * out_size, stream);

    const size_t ws_need = (size_t)2 * B_SZ * NPTS * sizeof(float);  // 512 KB
    if (ws_size >= ws_need) {
        // 0x7F bytes -> float 3.39e38: larger than any real squared distance.
        hipMemsetAsync(d_ws, 0x7F, ws_need, stream);
        chamfer_min_kernel<2, true>
            <<<2 * B_SZ * QCHUNKS * 2, BLOCK, 0, stream>>>(x, y, (unsigned int*)d_ws, out);
        chamfer_reduce_kernel
            <<<(2 * B_SZ * NPTS / 4) / 256, 256, 0, stream>>>((const float*)d_ws, out);
    } else {
        chamfer_min_kernel<1, false>
            <<<2 * B_SZ * QCHUNKS, BLOCK, 0, stream>>>(x, y, nullptr, out);
    }
}

// Round 3
// 82.595 us; speedup vs baseline: 2.5929x; 1.2055x over previous
//
#include <hip/hip_runtime.h>

// Chamfer loss: B=32, N=M=2048, D=3, fp32 in, scalar fp32 out.
// loss = sum_b [ sum_m min_n d2 + sum_n min_m d2 ] / B
//
// v3: VALU-op reduction + occupancy.
//  - Dot form: stage (px,py,pz,h=0.5*|p|^2); score s = h - q.p via 3 fma
//    (neg input modifiers are free) + 1 min = 4 VALU/pair vs 7 for the
//    direct diff form. d2 = max(0, 2*s_min + |q|^2) reconstructed once per
//    query (min is monotone, so this commutes with the cross-shard min).
//  - QPT=4 queries/thread: 1 broadcast ds_read_b128 per 16 VALU ops, 4
//    independent min chains for ILP.
//  - SSPLIT=8 staged shards -> 1024 blocks x 256, 4KB LDS, 4 waves/SIMD.
//    Per-shard partials stored (no atomics) to a 4MB ws slab; reduce kernel
//    does min-over-shards then sum. atomicMin / single-shard fallbacks.

constexpr int B_SZ    = 32;
constexpr int NPTS    = 2048;
constexpr int BLOCK   = 256;
constexpr int QPT     = 4;                  // queries per thread
constexpr int QBLK    = BLOCK * QPT;        // 1024
constexpr int QCHUNKS = NPTS / QBLK;        // 2
constexpr int SSPLIT  = 8;                  // staged-cloud shards
constexpr int NQ      = 2 * B_SZ * NPTS;    // 131072 query slots (both dirs)

template <int SSP, int MODE>  // MODE 0=store partials, 1=atomicMin, 2=direct sum
__global__ __launch_bounds__(BLOCK, 4)
void chamfer_min_kernel(const float* __restrict__ x, const float* __restrict__ y,
                        float* __restrict__ ws, float* __restrict__ out) {
    constexpr int SPTS = NPTS / SSP;
    __shared__ float4 pts[SPTS];
    __shared__ float  wsum[BLOCK / 64];

    const int id  = blockIdx.x;
    const int sh  = id % SSP;
    int t         = id / SSP;
    const int qc  = t % QCHUNKS;  t /= QCHUNKS;
    const int b   = t % B_SZ;
    const int dir = t / B_SZ;

    const float* qb = (dir == 0) ? x : y;
    const float* pb = (dir == 0) ? y : x;
    const float* q  = qb + (size_t)b * NPTS * 3;
    const float* p  = pb + (size_t)b * NPTS * 3 + sh * SPTS * 3;

    // Stage shard (coalesced), then fill w = 0.5*|p|^2.
    for (int idx = threadIdx.x; idx < SPTS * 3; idx += BLOCK) {
        int pt = idx / 3;
        int c  = idx - pt * 3;
        ((float*)&pts[pt])[c] = p[idx];
    }
    __syncthreads();
    for (int pt = threadIdx.x; pt < SPTS; pt += BLOCK) {
        float4 v = pts[pt];
        pts[pt].w = 0.5f * fmaf(v.x, v.x, fmaf(v.y, v.y, v.z * v.z));
    }
    __syncthreads();

    // Load QPT queries (BLOCK-strided -> coalesced-ish 12B/lane).
    float qx[QPT], qy[QPT], qz[QPT], q2[QPT], best[QPT];
    const int qi0 = qc * QBLK + threadIdx.x;
    #pragma unroll
    for (int k = 0; k < QPT; ++k) {
        int qi = qi0 + k * BLOCK;
        qx[k] = q[qi * 3 + 0];
        qy[k] = q[qi * 3 + 1];
        qz[k] = q[qi * 3 + 2];
        q2[k] = fmaf(qx[k], qx[k], fmaf(qy[k], qy[k], qz[k] * qz[k]));
        best[k] = 3.0e38f;
    }

    // Main scan: 2 points per body (min3 fusion), broadcast LDS reads.
    #pragma unroll 4
    for (int n = 0; n < SPTS; n += 2) {
        float4 pa = pts[n];
        float4 pc = pts[n + 1];
        #pragma unroll
        for (int k = 0; k < QPT; ++k) {
            float sa = fmaf(-qx[k], pa.x, fmaf(-qy[k], pa.y, fmaf(-qz[k], pa.z, pa.w)));
            float sb = fmaf(-qx[k], pc.x, fmaf(-qy[k], pc.y, fmaf(-qz[k], pc.z, pc.w)));
            best[k] = fminf(fminf(best[k], sa), sb);
        }
    }

    if (MODE == 0) {
        #pragma unroll
        for (int k = 0; k < QPT; ++k) {
            int qi = qi0 + k * BLOCK;
            float d = fmaxf(0.0f, fmaf(2.0f, best[k], q2[k]));
            ws[(size_t)sh * NQ + (size_t)(dir * B_SZ + b) * NPTS + qi] = d;
        }
    } else if (MODE == 1) {
        // uint atomicMin is order-preserving for non-negative floats.
        #pragma unroll
        for (int k = 0; k < QPT; ++k) {
            int qi = qi0 + k * BLOCK;
            float d = fmaxf(0.0f, fmaf(2.0f, best[k], q2[k]));
            atomicMin((unsigned int*)ws + (size_t)(dir * B_SZ + b) * NPTS + qi,
                      __float_as_uint(d));
        }
    } else {
        // SSP==1: mins complete, sum directly.
        float s = 0.0f;
        #pragma unroll
        for (int k = 0; k < QPT; ++k)
            s += fmaxf(0.0f, fmaf(2.0f, best[k], q2[k]));
        #pragma unroll
        for (int off = 32; off > 0; off >>= 1) s += __shfl_down(s, off, 64);
        if ((threadIdx.x & 63) == 0) wsum[threadIdx.x >> 6] = s;
        __syncthreads();
        if (threadIdx.x == 0) {
            float tt = 0.f;
            #pragma unroll
            for (int w = 0; w < BLOCK / 64; ++w) tt += wsum[w];
            atomicAdd(out, tt * (1.0f / B_SZ));
        }
    }
}

// MODE 0 reduce: min over SSPLIT shards, then sum. 131072/4/256 = 128 blocks.
__global__ __launch_bounds__(256)
void chamfer_reduce_min_kernel(const float* __restrict__ ws, float* __restrict__ out) {
    __shared__ float wsum[4];
    const int i = blockIdx.x * 256 + threadIdx.x;
    float4 m = ((const float4*)ws)[i];
    #pragma unroll
    for (int s = 1; s < SSPLIT; ++s) {
        float4 v = ((const float4*)(ws + (size_t)s * NQ))[i];
        m.x = fminf(m.x, v.x); m.y = fminf(m.y, v.y);
        m.z = fminf(m.z, v.z); m.w = fminf(m.w, v.w);
    }
    float s = (m.x + m.y) + (m.z + m.w);
    #pragma unroll
    for (int off = 32; off > 0; off >>= 1) s += __shfl_down(s, off, 64);
    if ((threadIdx.x & 63) == 0) wsum[threadIdx.x >> 6] = s;
    __syncthreads();
    if (threadIdx.x == 0) {
        float t = (wsum[0] + wsum[1]) + (wsum[2] + wsum[3]);
        atomicAdd(out, t * (1.0f / B_SZ));
    }
}

// MODE 1 reduce: ws already holds final per-query mins; just sum.
__global__ __launch_bounds__(256)
void chamfer_reduce_sum_kernel(const float* __restrict__ ws, float* __restrict__ out) {
    __shared__ float wsum[4];
    const int i = blockIdx.x * 256 + threadIdx.x;
    float4 v = ((const float4*)ws)[i];
    float s = (v.x + v.y) + (v.z + v.w);
    #pragma unroll
    for (int off = 32; off > 0; off >>= 1) s += __shfl_down(s, off, 64);
    if ((threadIdx.x & 63) == 0) wsum[threadIdx.x >> 6] = s;
    __syncthreads();
    if (threadIdx.x == 0) {
        float t = (wsum[0] + wsum[1]) + (wsum[2] + wsum[3]);
        atomicAdd(out, t * (1.0f / B_SZ));
    }
}

extern "C" void kernel_launch(void* const* d_in, const int* in_sizes, int n_in,
                              void* d_out, int out_size, void* d_ws, size_t ws_size,
                              hipStream_t stream) {
    const float* x = (const float*)d_in[0];
    const float* y = (const float*)d_in[1];
    float* out = (float*)d_out;

    hipMemsetAsync(out, 0, sizeof(float) * out_size, stream);

    const size_t ws_store  = (size_t)SSPLIT * NQ * sizeof(float);  // 4 MB
    const size_t ws_atomic = (size_t)NQ * sizeof(float);           // 512 KB

    if (ws_size >= ws_store) {
        chamfer_min_kernel<SSPLIT, 0>
            <<<2 * B_SZ * QCHUNKS * SSPLIT, BLOCK, 0, stream>>>(x, y, (float*)d_ws, out);
        chamfer_reduce_min_kernel
            <<<NQ / 4 / 256, 256, 0, stream>>>((const float*)d_ws, out);
    } else if (ws_size >= ws_atomic) {
        hipMemsetAsync(d_ws, 0x7F, ws_atomic, stream);  // 3.39e38 sentinels
        chamfer_min_kernel<SSPLIT, 1>
            <<<2 * B_SZ * QCHUNKS * SSPLIT, BLOCK, 0, stream>>>(x, y, (float*)d_ws, out);
        chamfer_reduce_sum_kernel
            <<<NQ / 4 / 256, 256, 0, stream>>>((const float*)d_ws, out);
    } else {
        chamfer_min_kernel<1, 2>
            <<<2 * B_SZ * QCHUNKS, BLOCK, 0, stream>>>(x, y, nullptr, out);
    }
}